// Round 1
// baseline (219.638 us; speedup 1.0000x reference)
//
#include <hip/hip_runtime.h>

// MXFP6 quant-dequant (straight-through forward):
//   per 32-elem block: scale = 2^floor(log2(max(|x|, 1e-8)))
//   q = clip(rne(x/scale * 15), -15, 15); out = (q/15) * scale
//
// Mapping: 1 MX block = 32 consecutive floats = 8 lanes x float4.
// Block absmax via 3x shfl_xor within aligned 8-lane groups.
// floor(log2)/exp2 done exactly by masking the fp32 exponent field.

__global__ __launch_bounds__(256) void mxfp6_qdq_kernel(
    const float4* __restrict__ x, float4* __restrict__ out, int n4) {
  int i = blockIdx.x * blockDim.x + threadIdx.x;
  if (i >= n4) return;

  float4 v = x[i];

  float a = fmaxf(fmaxf(fabsf(v.x), fabsf(v.y)),
                  fmaxf(fabsf(v.z), fabsf(v.w)));
  // absmax across the 8 lanes sharing this MX block (lanes 8k..8k+7)
  a = fmaxf(a, __shfl_xor(a, 1));
  a = fmaxf(a, __shfl_xor(a, 2));
  a = fmaxf(a, __shfl_xor(a, 4));
  a = fmaxf(a, 1e-8f);

  // scale = 2^floor(log2(a)) == exponent part of a (a is normal, >= 1e-8)
  float scale = __uint_as_float(__float_as_uint(a) & 0x7f800000u);
  float inv = 15.0f / scale;           // exact: 15 / power-of-2
  float rs  = scale * (1.0f / 15.0f);  // <=2 ulp vs ref's (q/15)*scale

  float4 o;
  o.x = fminf(fmaxf(rintf(v.x * inv), -15.0f), 15.0f) * rs;
  o.y = fminf(fmaxf(rintf(v.y * inv), -15.0f), 15.0f) * rs;
  o.z = fminf(fmaxf(rintf(v.z * inv), -15.0f), 15.0f) * rs;
  o.w = fminf(fmaxf(rintf(v.w * inv), -15.0f), 15.0f) * rs;
  out[i] = o;
}

extern "C" void kernel_launch(void* const* d_in, const int* in_sizes, int n_in,
                              void* d_out, int out_size, void* d_ws, size_t ws_size,
                              hipStream_t stream) {
  const float* x = (const float*)d_in[0];
  float* out = (float*)d_out;
  int n = in_sizes[0];          // 4096*8192, divisible by 32
  int n4 = n / 4;               // float4 count
  int block = 256;
  int grid = (n4 + block - 1) / block;
  mxfp6_qdq_kernel<<<grid, block, 0, stream>>>(
      (const float4*)x, (float4*)out, n4);
}